// Round 16
// baseline (879.462 us; speedup 1.0000x reference)
//
#include <hip/hip_runtime.h>
#include <math.h>

#define N_NODES 65536
#define F_DIM 512
#define H_DIM 256
#define E_EDGES 1048576
#define R_REPS 512

typedef _Float16 f16x8 __attribute__((ext_vector_type(8)));
typedef _Float16 f16x4 __attribute__((ext_vector_type(4)));
typedef float f32x4_t __attribute__((ext_vector_type(4)));

__device__ __forceinline__ float selu_f(float x) {
    const float SC = 1.0507009873554804934f;
    const float AL = 1.6732632423543772848f;
    return x > 0.f ? SC * x : SC * AL * expm1f(x);
}

__device__ __forceinline__ void split8v(float4 v0, float4 v1, f16x8* hi, f16x8* lo) {
    f16x8 h, l;
    h[0] = (_Float16)v0.x; h[1] = (_Float16)v0.y; h[2] = (_Float16)v0.z; h[3] = (_Float16)v0.w;
    h[4] = (_Float16)v1.x; h[5] = (_Float16)v1.y; h[6] = (_Float16)v1.z; h[7] = (_Float16)v1.w;
    l[0] = (_Float16)(v0.x - (float)h[0]); l[1] = (_Float16)(v0.y - (float)h[1]);
    l[2] = (_Float16)(v0.z - (float)h[2]); l[3] = (_Float16)(v0.w - (float)h[3]);
    l[4] = (_Float16)(v1.x - (float)h[4]); l[5] = (_Float16)(v1.y - (float)h[5]);
    l[6] = (_Float16)(v1.z - (float)h[6]); l[7] = (_Float16)(v1.w - (float)h[7]);
    *hi = h; *lo = l;
}

// 64-lane bitonic sort (ascending) — bucket order = f(contents) => determinism
__device__ __forceinline__ int wave_sort64(int v, int lane) {
    #pragma unroll
    for (int k = 2; k <= 64; k <<= 1) {
        #pragma unroll
        for (int j = k >> 1; j > 0; j >>= 1) {
            int p = __shfl_xor(v, j);
            bool takeMin = (((lane & j) == 0) == ((lane & k) == 0));
            int mn = min(v, p), mx = max(v, p);
            v = takeMin ? mn : mx;
        }
    }
    return v;
}

__global__ void k_init(int* cnt_s, int* cnt_r, float* colsum,
                       unsigned* node_min, unsigned long long* center_min,
                       double* loss_acc) {
    int i = blockIdx.x * 256 + threadIdx.x;
    if (i < N_NODES) { cnt_s[i] = 0; cnt_r[i] = 0; node_min[i] = 0x7F800000u; }
    if (i < H_DIM) colsum[i] = 0.f;
    if (i < R_REPS) center_min[i] = ~0ull;
    if (i == 0) *loss_acc = 0.0;
}

__global__ void k_degree(const int* __restrict__ senders, const int* __restrict__ receivers,
                         int* __restrict__ cnt_s, int* __restrict__ cnt_r) {
    int e = blockIdx.x * 256 + threadIdx.x;
    if (e < E_EDGES) {
        atomicAdd(&cnt_s[senders[e]], 1);
        atomicAdd(&cnt_r[receivers[e]], 1);
    }
}

__global__ void k_invsqrt(const int* __restrict__ cnt_s, const int* __restrict__ cnt_r,
                          float* __restrict__ inv_s, float* __restrict__ inv_r) {
    int i = blockIdx.x * 256 + threadIdx.x;
    if (i < N_NODES) {
        inv_s[i] = 1.0f / sqrtf(fmaxf((float)cnt_s[i], 1.f));
        inv_r[i] = 1.0f / sqrtf(fmaxf((float)cnt_r[i], 1.f));
    }
}

__global__ __launch_bounds__(1024) void k_scan(const int* __restrict__ cnt,
                                               int* __restrict__ row_ptr,
                                               int* __restrict__ cursor) {
    __shared__ int part[1024];
    int t = threadIdx.x;
    int base = t * 64;
    int s = 0;
    #pragma unroll 8
    for (int i = 0; i < 64; ++i) s += cnt[base + i];
    part[t] = s;
    __syncthreads();
    for (int off = 1; off < 1024; off <<= 1) {
        int other = (t >= off) ? part[t - off] : 0;
        __syncthreads();
        part[t] += other;
        __syncthreads();
    }
    int run = part[t] - s;
    for (int i = 0; i < 64; ++i) {
        row_ptr[base + i] = run;
        cursor[base + i] = run;
        run += cnt[base + i];
    }
    if (t == 1023) row_ptr[N_NODES] = run;
}

__global__ void k_fill(const int* __restrict__ senders, const int* __restrict__ receivers,
                       int* __restrict__ cursor, int* __restrict__ csr_send) {
    int e = blockIdx.x * 256 + threadIdx.x;
    if (e < E_EDGES) {
        int pos = atomicAdd(&cursor[receivers[e]], 1);
        csr_send[pos] = senders[e];
    }
}

// W[512][256] -> WT_hi/lo [256][512]
__global__ void k_splitWT(const float* __restrict__ W, _Float16* __restrict__ hiT,
                          _Float16* __restrict__ loT) {
    int idx = blockIdx.x * 256 + threadIdx.x;
    int n = idx & (H_DIM - 1);
    int k = idx >> 8;
    float x = W[(size_t)k * H_DIM + n];
    _Float16 h = (_Float16)x;
    hiT[(size_t)n * F_DIM + k] = h;
    loT[(size_t)n * F_DIM + k] = (_Float16)(x - (float)h);
}

// generic elementwise split (centers)
__global__ void k_split(const float* __restrict__ src, _Float16* __restrict__ hi,
                        _Float16* __restrict__ lo, int n4) {
    int i = blockIdx.x * 256 + threadIdx.x;
    if (i >= n4) return;
    float4 v = ((const float4*)src)[i];
    f16x4 h, l;
    h[0] = (_Float16)v.x; h[1] = (_Float16)v.y; h[2] = (_Float16)v.z; h[3] = (_Float16)v.w;
    l[0] = (_Float16)(v.x - (float)h[0]);
    l[1] = (_Float16)(v.y - (float)h[1]);
    l[2] = (_Float16)(v.z - (float)h[2]);
    l[3] = (_Float16)(v.w - (float)h[3]);
    ((f16x4*)hi)[i] = h;
    ((f16x4*)lo)[i] = l;
}

#define LDP 36   // stride 72B = 18 words, gcd(18,32)=2

#define MFMA3(accv, AH, AL, BH, BL) \
    accv = __builtin_amdgcn_mfma_f32_16x16x32_f16(AH, BH, accv, 0, 0, 0); \
    accv = __builtin_amdgcn_mfma_f32_16x16x32_f16(AH, BL, accv, 0, 0, 0); \
    accv = __builtin_amdgcn_mfma_f32_16x16x32_f16(AL, BH, accv, 0, 0, 0);

#define MFMA_CORE \
    f16x8 ah[4], al[4]; \
    _Pragma("unroll") \
    for (int mi = 0; mi < 4; ++mi) { \
        ah[mi] = *(f16x8*)&Ah[wm * 64 + mi * 16 + lrow][kg * 8]; \
        al[mi] = *(f16x8*)&Al[wm * 64 + mi * 16 + lrow][kg * 8]; \
    } \
    _Pragma("unroll") \
    for (int ni = 0; ni < 4; ++ni) { \
        f16x8 bh = *(f16x8*)&Bh[wn * 64 + ni * 16 + lrow][kg * 8]; \
        f16x8 bl = *(f16x8*)&Bl[wn * 64 + ni * 16 + lrow][kg * 8]; \
        _Pragma("unroll") \
        for (int mi = 0; mi < 4; ++mi) { MFMA3(acc[mi][ni], ah[mi], al[mi], bh, bl) } \
    }

#define WRITE_A_REGS { \
    f16x8 h0, l0, h1, l1; \
    split8v(pa0, pa1, &h0, &l0); \
    split8v(pa2, pa3, &h1, &l1); \
    *(f16x8*)&Ah[sr][skh] = h0; *(f16x8*)&Ah[sr][skh + 8] = h1; \
    *(f16x8*)&Al[sr][skh] = l0; *(f16x8*)&Al[sr][skh + 8] = l1; }

// X = (A @ WT^T + bias) * inv_s; A f32 fused-split (pipelined), WT pre-split f16 (pipelined)
// XCD-swizzled 1-D grid: sibling n-tiles of one m land on the same XCD adjacently.
__global__ __launch_bounds__(256) void k_gemm_mfma(
    const float* __restrict__ A,
    const _Float16* __restrict__ BThi, const _Float16* __restrict__ BTlo,
    const float* __restrict__ bias, const float* __restrict__ inv_s,
    float* __restrict__ X, int K) {
    __shared__ _Float16 Ah[128][LDP], Al[128][LDP], Bh[128][LDP], Bl[128][LDP];
    const int t = threadIdx.x;
    const int lane = t & 63;
    const int wm = (t >> 6) >> 1, wn = (t >> 6) & 1;
    const int lrow = lane & 15, kg = lane >> 4;
    const int bid = blockIdx.x;                       // 0..1023
    const int m0 = (((bid >> 4) << 3) | (bid & 7)) * 128;
    const int n0 = ((bid >> 3) & 1) * 128;
    const int sr = t >> 1, skh = (t & 1) << 4;
    const float* gA = A + (size_t)(m0 + sr) * K + skh;
    const _Float16* gBh = BThi + (size_t)(n0 + sr) * K + skh;
    const _Float16* gBl = BTlo + (size_t)(n0 + sr) * K + skh;
    f32x4_t acc[4][4] = {};
    float4 pa0, pa1, pa2, pa3;
    // prologue: stage tile 0
    pa0 = *(const float4*)(gA + 0);  pa1 = *(const float4*)(gA + 4);
    pa2 = *(const float4*)(gA + 8);  pa3 = *(const float4*)(gA + 12);
    WRITE_A_REGS
    *(float4*)&Bh[sr][skh]     = *(const float4*)(gBh + 0);
    *(float4*)&Bh[sr][skh + 8] = *(const float4*)(gBh + 8);
    *(float4*)&Bl[sr][skh]     = *(const float4*)(gBl + 0);
    *(float4*)&Bl[sr][skh + 8] = *(const float4*)(gBl + 8);
    for (int k0 = 0; k0 < K; k0 += 32) {
        __syncthreads();                       // LDS tile k0 ready
        const bool more = (k0 + 32) < K;
        float4 qb0, qb1, qb2, qb3;
        if (more) {                            // loads for k0+32 hide under MFMA
            pa0 = *(const float4*)(gA + k0 + 32);
            pa1 = *(const float4*)(gA + k0 + 36);
            pa2 = *(const float4*)(gA + k0 + 40);
            pa3 = *(const float4*)(gA + k0 + 44);
            qb0 = *(const float4*)(gBh + k0 + 32);
            qb1 = *(const float4*)(gBh + k0 + 40);
            qb2 = *(const float4*)(gBl + k0 + 32);
            qb3 = *(const float4*)(gBl + k0 + 40);
        }
        MFMA_CORE
        __syncthreads();                       // all waves done reading tile k0
        if (more) {
            WRITE_A_REGS
            *(float4*)&Bh[sr][skh]     = qb0;
            *(float4*)&Bh[sr][skh + 8] = qb1;
            *(float4*)&Bl[sr][skh]     = qb2;
            *(float4*)&Bl[sr][skh + 8] = qb3;
        }
    }
    #pragma unroll
    for (int ni = 0; ni < 4; ++ni) {
        int col = n0 + wn * 64 + ni * 16 + lrow;
        float bc = bias[col];
        #pragma unroll
        for (int mi = 0; mi < 4; ++mi) {
            #pragma unroll
            for (int j = 0; j < 4; ++j) {
                int row = m0 + wm * 64 + mi * 16 + kg * 4 + j;
                X[(size_t)row * H_DIM + col] = (acc[mi][ni][j] + bc) * inv_s[row];
            }
        }
    }
}

// cluster: A=pre-split emb (f16), B=pre-split centers (f16); pure-copy staging, pipelined
__global__ __launch_bounds__(256) void k_cluster_mfma(
    const _Float16* __restrict__ Ehi, const _Float16* __restrict__ Elo,
    const _Float16* __restrict__ Chi, const _Float16* __restrict__ Clo,
    const float* __restrict__ e2, const float* __restrict__ c2,
    unsigned* __restrict__ node_min, unsigned long long* __restrict__ center_min) {
    __shared__ _Float16 Ah[128][LDP], Al[128][LDP], Bh[128][LDP], Bl[128][LDP];
    __shared__ unsigned s_nmin[128];
    __shared__ unsigned long long s_cmin[128];
    const int t = threadIdx.x;
    const int lane = t & 63;
    const int wm = (t >> 6) >> 1, wn = (t >> 6) & 1;
    const int lrow = lane & 15, kg = lane >> 4;
    const int bid = blockIdx.x;                       // 0..2047
    const int m0 = (((bid >> 5) << 3) | (bid & 7)) * 128;
    const int n0 = ((bid >> 3) & 3) * 128;
    const int sr = t >> 1, skh = (t & 1) << 4;
    const int K = H_DIM;
    const _Float16* gAh = Ehi + (size_t)(m0 + sr) * K + skh;
    const _Float16* gAl = Elo + (size_t)(m0 + sr) * K + skh;
    const _Float16* gBh = Chi + (size_t)(n0 + sr) * K + skh;
    const _Float16* gBl = Clo + (size_t)(n0 + sr) * K + skh;
    if (t < 128) { s_nmin[t] = 0x7F800000u; s_cmin[t] = ~0ull; }
    f32x4_t acc[4][4] = {};
    float4 pa0, pa1, pa2, pa3, pb0, pb1, pb2, pb3;   // each float4 = 8 f16
    // prologue: stage tile 0
    pa0 = *(const float4*)(gAh + 0); pa1 = *(const float4*)(gAh + 8);
    pa2 = *(const float4*)(gAl + 0); pa3 = *(const float4*)(gAl + 8);
    pb0 = *(const float4*)(gBh + 0); pb1 = *(const float4*)(gBh + 8);
    pb2 = *(const float4*)(gBl + 0); pb3 = *(const float4*)(gBl + 8);
    *(float4*)&Ah[sr][skh] = pa0; *(float4*)&Ah[sr][skh + 8] = pa1;
    *(float4*)&Al[sr][skh] = pa2; *(float4*)&Al[sr][skh + 8] = pa3;
    *(float4*)&Bh[sr][skh] = pb0; *(float4*)&Bh[sr][skh + 8] = pb1;
    *(float4*)&Bl[sr][skh] = pb2; *(float4*)&Bl[sr][skh + 8] = pb3;
    for (int k0 = 0; k0 < K; k0 += 32) {
        __syncthreads();
        const bool more = (k0 + 32) < K;
        if (more) {
            pa0 = *(const float4*)(gAh + k0 + 32); pa1 = *(const float4*)(gAh + k0 + 40);
            pa2 = *(const float4*)(gAl + k0 + 32); pa3 = *(const float4*)(gAl + k0 + 40);
            pb0 = *(const float4*)(gBh + k0 + 32); pb1 = *(const float4*)(gBh + k0 + 40);
            pb2 = *(const float4*)(gBl + k0 + 32); pb3 = *(const float4*)(gBl + k0 + 40);
        }
        MFMA_CORE
        __syncthreads();
        if (more) {
            *(float4*)&Ah[sr][skh] = pa0; *(float4*)&Ah[sr][skh + 8] = pa1;
            *(float4*)&Al[sr][skh] = pa2; *(float4*)&Al[sr][skh + 8] = pa3;
            *(float4*)&Bh[sr][skh] = pb0; *(float4*)&Bh[sr][skh + 8] = pb1;
            *(float4*)&Bl[sr][skh] = pb2; *(float4*)&Bl[sr][skh + 8] = pb3;
        }
    }
    float cv[4];
    #pragma unroll
    for (int ni = 0; ni < 4; ++ni) cv[ni] = c2[n0 + wn * 64 + ni * 16 + lrow];
    unsigned long long cb[4] = {~0ull, ~0ull, ~0ull, ~0ull};
    #pragma unroll
    for (int mi = 0; mi < 4; ++mi) {
        #pragma unroll
        for (int j = 0; j < 4; ++j) {
            int lr = wm * 64 + mi * 16 + kg * 4 + j;
            int row = m0 + lr;
            float ev = e2[row];
            float rmin = 3.402823466e+38f;
            #pragma unroll
            for (int ni = 0; ni < 4; ++ni) {
                float d2 = ev + cv[ni] - 2.f * acc[mi][ni][j];
                float d = sqrtf(fmaxf(d2, 1e-12f));
                rmin = fminf(rmin, d);
                unsigned long long pk = ((unsigned long long)__float_as_uint(d) << 32) | (unsigned)row;
                if (pk < cb[ni]) cb[ni] = pk;
            }
            atomicMin(&s_nmin[lr], __float_as_uint(rmin));
        }
    }
    #pragma unroll
    for (int ni = 0; ni < 4; ++ni)
        atomicMin(&s_cmin[wn * 64 + ni * 16 + lrow], cb[ni]);
    __syncthreads();
    if (t < 128) {
        atomicMin(&node_min[m0 + t], s_nmin[t]);
        atomicMin(&center_min[n0 + t], s_cmin[t]);
    }
}

// one wave per node; bucket chunk sorted -> bit-deterministic sum
__global__ __launch_bounds__(256) void k_agg1(
    const float* __restrict__ X, const int* __restrict__ csr_send,
    const int* __restrict__ row_ptr, const float* __restrict__ inv_r,
    float* __restrict__ out_emb) {
    int node = blockIdx.x * 4 + (threadIdx.x >> 6);
    int lane = threadIdx.x & 63;
    int beg = row_ptr[node], end = row_ptr[node + 1];
    float4 acc = {0.f, 0.f, 0.f, 0.f};
    for (int b = beg; b < end; b += 64) {
        int n = min(64, end - b);
        int myS = (lane < n) ? csr_send[b + lane] : 0x7FFFFFFF;
        myS = wave_sort64(myS, lane);
        for (int i = 0; i < n; ++i) {
            int s = __shfl(myS, i);
            float4 x = *(const float4*)&X[(size_t)s * H_DIM + (lane << 2)];
            acc.x += x.x; acc.y += x.y; acc.z += x.z; acc.w += x.w;
        }
    }
    float ir = inv_r[node];
    float4 o;
    o.x = selu_f(acc.x * ir);
    o.y = selu_f(acc.y * ir);
    o.z = selu_f(acc.z * ir);
    o.w = selu_f(acc.w * ir);
    *(float4*)&out_emb[(size_t)node * H_DIM + (lane << 2)] = o;
}

__global__ __launch_bounds__(256) void k_agg2(
    const float* __restrict__ X, const int* __restrict__ csr_send,
    const int* __restrict__ row_ptr, const float* __restrict__ inv_r,
    const float* __restrict__ v, float* __restrict__ out) {
    int node = blockIdx.x * 4 + (threadIdx.x >> 6);
    int lane = threadIdx.x & 63;
    int beg = row_ptr[node], end = row_ptr[node + 1];
    float4 acc = {0.f, 0.f, 0.f, 0.f};
    for (int b = beg; b < end; b += 64) {
        int n = min(64, end - b);
        int myS = (lane < n) ? csr_send[b + lane] : 0x7FFFFFFF;
        myS = wave_sort64(myS, lane);
        for (int i = 0; i < n; ++i) {
            int s = __shfl(myS, i);
            float4 x = *(const float4*)&X[(size_t)s * H_DIM + (lane << 2)];
            acc.x += x.x; acc.y += x.y; acc.z += x.z; acc.w += x.w;
        }
    }
    float ir = inv_r[node];
    float4 vv = *(const float4*)&v[lane << 2];
    float d = selu_f(acc.x * ir) * vv.x + selu_f(acc.y * ir) * vv.y
            + selu_f(acc.z * ir) * vv.z + selu_f(acc.w * ir) * vv.w;
    #pragma unroll
    for (int off = 32; off; off >>= 1) d += __shfl_down(d, off);
    if (lane == 0) out[node] = d;
}

__global__ __launch_bounds__(256) void k_colsum(const float* __restrict__ nodes1,
                                                float* __restrict__ colsum) {
    int t = threadIdx.x;
    size_t r0 = (size_t)blockIdx.x * 64;
    float s = 0.f;
    for (int r = 0; r < 64; ++r) s += nodes1[(r0 + r) * H_DIM + t];
    atomicAdd(&colsum[t], s);
}

__global__ void k_summary_v(const float* __restrict__ colsum, const float* __restrict__ Wb,
                            float* __restrict__ v) {
    __shared__ float s_sum[H_DIM];
    int t = threadIdx.x;
    float m = colsum[t] * (1.f / (float)N_NODES);
    s_sum[t] = 1.f / (1.f + expf(-m));
    __syncthreads();
    float acc = 0.f;
    for (int j = 0; j < H_DIM; ++j) acc += Wb[t * H_DIM + j] * s_sum[j];
    v[t] = acc;
}

// fused: logits, row-normalize in place, e2, and emit f16 hi/lo split of normalized emb
__global__ __launch_bounds__(256) void k_normrow(
    float* __restrict__ emb, const float* __restrict__ v,
    float* __restrict__ logits, float* __restrict__ e2,
    _Float16* __restrict__ ehi, _Float16* __restrict__ elo) {
    int row = blockIdx.x * 4 + (threadIdx.x >> 6);
    int lane = threadIdx.x & 63;
    float4 a = *(float4*)&emb[(size_t)row * H_DIM + (lane << 2)];
    float4 vv = *(const float4*)&v[lane << 2];
    float d = a.x * vv.x + a.y * vv.y + a.z * vv.z + a.w * vv.w;
    float ss = a.x * a.x + a.y * a.y + a.z * a.z + a.w * a.w;
    #pragma unroll
    for (int off = 32; off; off >>= 1) {
        d += __shfl_xor(d, off);
        ss += __shfl_xor(ss, off);
    }
    if (lane == 0) logits[row] = d;
    float inv = 1.f / sqrtf(ss);
    a.x *= inv; a.y *= inv; a.z *= inv; a.w *= inv;
    *(float4*)&emb[(size_t)row * H_DIM + (lane << 2)] = a;
    f16x4 h, l;
    h[0] = (_Float16)a.x; h[1] = (_Float16)a.y; h[2] = (_Float16)a.z; h[3] = (_Float16)a.w;
    l[0] = (_Float16)(a.x - (float)h[0]);
    l[1] = (_Float16)(a.y - (float)h[1]);
    l[2] = (_Float16)(a.z - (float)h[2]);
    l[3] = (_Float16)(a.w - (float)h[3]);
    *(f16x4*)&ehi[(size_t)row * H_DIM + (lane << 2)] = h;
    *(f16x4*)&elo[(size_t)row * H_DIM + (lane << 2)] = l;
    float s2 = a.x * a.x + a.y * a.y + a.z * a.z + a.w * a.w;
    #pragma unroll
    for (int off = 32; off; off >>= 1) s2 += __shfl_xor(s2, off);
    if (lane == 0) e2[row] = s2;
}

__global__ __launch_bounds__(256) void k_c2(const float* __restrict__ centers,
                                            float* __restrict__ c2) {
    int row = blockIdx.x * 4 + (threadIdx.x >> 6);
    int lane = threadIdx.x & 63;
    float4 a = *(const float4*)&centers[(size_t)row * H_DIM + (lane << 2)];
    float ss = a.x * a.x + a.y * a.y + a.z * a.z + a.w * a.w;
    #pragma unroll
    for (int off = 32; off; off >>= 1) ss += __shfl_xor(ss, off);
    if (lane == 0) c2[row] = ss;
}

__global__ __launch_bounds__(256) void k_loss(const unsigned* __restrict__ node_min,
                                              double* __restrict__ acc) {
    int i = blockIdx.x * 256 + threadIdx.x;
    float s = __uint_as_float(node_min[i]);
    #pragma unroll
    for (int off = 32; off; off >>= 1) s += __shfl_down(s, off);
    __shared__ float ws[4];
    int lane = threadIdx.x & 63, w = threadIdx.x >> 6;
    if (lane == 0) ws[w] = s;
    __syncthreads();
    if (threadIdx.x == 0) {
        float tot = ws[0] + ws[1] + ws[2] + ws[3];
        atomicAdd(acc, (double)tot);
    }
}

__global__ void k_finalize(const unsigned long long* __restrict__ center_min,
                           const double* __restrict__ loss_acc,
                           float* __restrict__ rep_out, float* __restrict__ loss_out) {
    int t = blockIdx.x * 256 + threadIdx.x;
    if (t < R_REPS) rep_out[t] = (float)(unsigned)(center_min[t] & 0xFFFFFFFFull);
    if (t == 0) *loss_out = (float)(*loss_acc);
}

extern "C" void kernel_launch(void* const* d_in, const int* in_sizes, int n_in,
                              void* d_out, int out_size, void* d_ws, size_t ws_size,
                              hipStream_t stream) {
    const float* nodes   = (const float*)d_in[0];
    const float* c_nodes = (const float*)d_in[1];
    const int* senders   = (const int*)d_in[2];
    const int* receivers = (const int*)d_in[3];
    const float* W       = (const float*)d_in[4];
    const float* bias    = (const float*)d_in[5];
    const float* Wb      = (const float*)d_in[6];
    const float* centers = (const float*)d_in[7];

    float* out = (float*)d_out;
    float* out_emb    = out;
    float* out_cent   = out + (size_t)N_NODES * H_DIM;
    float* out_rep    = out_cent + (size_t)R_REPS * H_DIM;
    float* out_loss   = out_rep + R_REPS;
    float* out_logits = out_loss + 1;

    char* wp = (char*)d_ws;
    unsigned long long* center_min = (unsigned long long*)wp; wp += (size_t)R_REPS * 8;
    double* loss_acc = (double*)wp;             wp += 8;
    float* X = (float*)wp;                      wp += (size_t)N_NODES * H_DIM * 4;
    int* csr_send = (int*)wp;                   wp += (size_t)E_EDGES * 4;
    int* row_ptr = (int*)wp;                    wp += (size_t)(N_NODES + 2) * 4;
    int* cursor = (int*)wp;                     wp += (size_t)N_NODES * 4;
    int* cnt_s = (int*)wp;                      wp += (size_t)N_NODES * 4;
    int* cnt_r = (int*)wp;                      wp += (size_t)N_NODES * 4;
    float* inv_s = (float*)wp;                  wp += (size_t)N_NODES * 4;
    float* inv_r = (float*)wp;                  wp += (size_t)N_NODES * 4;
    float* colsum = (float*)wp;                 wp += (size_t)H_DIM * 4;
    float* v = (float*)wp;                      wp += (size_t)H_DIM * 4;
    float* e2 = (float*)wp;                     wp += (size_t)N_NODES * 4;
    float* c2 = (float*)wp;                     wp += (size_t)R_REPS * 4;
    unsigned* node_min = (unsigned*)wp;         wp += (size_t)N_NODES * 4;
    _Float16* WhiT = (_Float16*)wp;             wp += (size_t)H_DIM * F_DIM * 2;
    _Float16* WloT = (_Float16*)wp;             wp += (size_t)H_DIM * F_DIM * 2;
    _Float16* Chi = (_Float16*)wp;              wp += (size_t)R_REPS * H_DIM * 2;
    _Float16* Clo = (_Float16*)wp;              wp += (size_t)R_REPS * H_DIM * 2;
    _Float16* Ehi = (_Float16*)wp;              wp += (size_t)N_NODES * H_DIM * 2;
    _Float16* Elo = (_Float16*)wp;              wp += (size_t)N_NODES * H_DIM * 2;

    k_init<<<N_NODES / 256, 256, 0, stream>>>(cnt_s, cnt_r, colsum, node_min, center_min, loss_acc);
    k_degree<<<E_EDGES / 256, 256, 0, stream>>>(senders, receivers, cnt_s, cnt_r);
    k_invsqrt<<<N_NODES / 256, 256, 0, stream>>>(cnt_s, cnt_r, inv_s, inv_r);
    k_scan<<<1, 1024, 0, stream>>>(cnt_r, row_ptr, cursor);
    k_fill<<<E_EDGES / 256, 256, 0, stream>>>(senders, receivers, cursor, csr_send);
    k_splitWT<<<(F_DIM * H_DIM) / 256, 256, 0, stream>>>(W, WhiT, WloT);
    k_split<<<(R_REPS * H_DIM / 4) / 256, 256, 0, stream>>>(centers, Chi, Clo, R_REPS * H_DIM / 4);

    // GCN1 (1-D XCD-swizzled grid: 1024 blocks)
    k_gemm_mfma<<<1024, 256, 0, stream>>>(nodes, WhiT, WloT, bias, inv_s, X, F_DIM);
    k_agg1<<<N_NODES / 4, 256, 0, stream>>>(X, csr_send, row_ptr, inv_r, out_emb);

    k_colsum<<<N_NODES / 64, 256, 0, stream>>>(out_emb, colsum);
    k_summary_v<<<1, 256, 0, stream>>>(colsum, Wb, v);
    k_normrow<<<N_NODES / 4, 256, 0, stream>>>(out_emb, v, out_logits, e2, Ehi, Elo);
    k_c2<<<R_REPS / 4, 256, 0, stream>>>(centers, c2);

    // cluster (1-D XCD-swizzled grid: 2048 blocks; all-f16 staging)
    k_cluster_mfma<<<2048, 256, 0, stream>>>(Ehi, Elo, Chi, Clo, e2, c2, node_min, center_min);
    k_loss<<<N_NODES / 256, 256, 0, stream>>>(node_min, loss_acc);
    k_finalize<<<2, 256, 0, stream>>>(center_min, loss_acc, out_rep, out_loss);
    hipMemcpyAsync(out_cent, centers, (size_t)R_REPS * H_DIM * 4, hipMemcpyDeviceToDevice, stream);

    // GCN2 (reuse X; nodes2 never materialized)
    k_gemm_mfma<<<1024, 256, 0, stream>>>(c_nodes, WhiT, WloT, bias, inv_s, X, F_DIM);
    k_agg2<<<N_NODES / 4, 256, 0, stream>>>(X, csr_send, row_ptr, inv_r, v, out_logits + N_NODES);
}

// Round 17
// 857.600 us; speedup vs baseline: 1.0255x; 1.0255x over previous
//
#include <hip/hip_runtime.h>
#include <math.h>

#define N_NODES 65536
#define F_DIM 512
#define H_DIM 256
#define E_EDGES 1048576
#define R_REPS 512

typedef _Float16 f16x8 __attribute__((ext_vector_type(8)));
typedef float f32x4_t __attribute__((ext_vector_type(4)));

__device__ __forceinline__ float selu_f(float x) {
    const float SC = 1.0507009873554804934f;
    const float AL = 1.6732632423543772848f;
    return x > 0.f ? SC * x : SC * AL * expm1f(x);
}

__device__ __forceinline__ void split8v(float4 v0, float4 v1, f16x8* hi, f16x8* lo) {
    f16x8 h, l;
    h[0] = (_Float16)v0.x; h[1] = (_Float16)v0.y; h[2] = (_Float16)v0.z; h[3] = (_Float16)v0.w;
    h[4] = (_Float16)v1.x; h[5] = (_Float16)v1.y; h[6] = (_Float16)v1.z; h[7] = (_Float16)v1.w;
    l[0] = (_Float16)(v0.x - (float)h[0]); l[1] = (_Float16)(v0.y - (float)h[1]);
    l[2] = (_Float16)(v0.z - (float)h[2]); l[3] = (_Float16)(v0.w - (float)h[3]);
    l[4] = (_Float16)(v1.x - (float)h[4]); l[5] = (_Float16)(v1.y - (float)h[5]);
    l[6] = (_Float16)(v1.z - (float)h[6]); l[7] = (_Float16)(v1.w - (float)h[7]);
    *hi = h; *lo = l;
}

// 64-lane bitonic sort (ascending) — bucket order = f(contents) => determinism
__device__ __forceinline__ int wave_sort64(int v, int lane) {
    #pragma unroll
    for (int k = 2; k <= 64; k <<= 1) {
        #pragma unroll
        for (int j = k >> 1; j > 0; j >>= 1) {
            int p = __shfl_xor(v, j);
            bool takeMin = (((lane & j) == 0) == ((lane & k) == 0));
            int mn = min(v, p), mx = max(v, p);
            v = takeMin ? mn : mx;
        }
    }
    return v;
}

__global__ void k_init(int* cnt_s, int* cnt_r, float* colsum,
                       unsigned* node_min, unsigned long long* center_min,
                       double* loss_acc) {
    int i = blockIdx.x * 256 + threadIdx.x;
    if (i < N_NODES) { cnt_s[i] = 0; cnt_r[i] = 0; node_min[i] = 0x7F800000u; }
    if (i < H_DIM) colsum[i] = 0.f;
    if (i < R_REPS) center_min[i] = ~0ull;
    if (i == 0) *loss_acc = 0.0;
}

__global__ void k_degree(const int* __restrict__ senders, const int* __restrict__ receivers,
                         int* __restrict__ cnt_s, int* __restrict__ cnt_r) {
    int e = blockIdx.x * 256 + threadIdx.x;
    if (e < E_EDGES) {
        atomicAdd(&cnt_s[senders[e]], 1);
        atomicAdd(&cnt_r[receivers[e]], 1);
    }
}

__global__ void k_invsqrt(const int* __restrict__ cnt_s, const int* __restrict__ cnt_r,
                          float* __restrict__ inv_s, float* __restrict__ inv_r) {
    int i = blockIdx.x * 256 + threadIdx.x;
    if (i < N_NODES) {
        inv_s[i] = 1.0f / sqrtf(fmaxf((float)cnt_s[i], 1.f));
        inv_r[i] = 1.0f / sqrtf(fmaxf((float)cnt_r[i], 1.f));
    }
}

__global__ __launch_bounds__(1024) void k_scan(const int* __restrict__ cnt,
                                               int* __restrict__ row_ptr,
                                               int* __restrict__ cursor) {
    __shared__ int part[1024];
    int t = threadIdx.x;
    int base = t * 64;
    int s = 0;
    #pragma unroll 8
    for (int i = 0; i < 64; ++i) s += cnt[base + i];
    part[t] = s;
    __syncthreads();
    for (int off = 1; off < 1024; off <<= 1) {
        int other = (t >= off) ? part[t - off] : 0;
        __syncthreads();
        part[t] += other;
        __syncthreads();
    }
    int run = part[t] - s;
    for (int i = 0; i < 64; ++i) {
        row_ptr[base + i] = run;
        cursor[base + i] = run;
        run += cnt[base + i];
    }
    if (t == 1023) row_ptr[N_NODES] = run;
}

__global__ void k_fill(const int* __restrict__ senders, const int* __restrict__ receivers,
                       int* __restrict__ cursor, int* __restrict__ csr_send) {
    int e = blockIdx.x * 256 + threadIdx.x;
    if (e < E_EDGES) {
        int pos = atomicAdd(&cursor[receivers[e]], 1);
        csr_send[pos] = senders[e];
    }
}

// W[512][256] -> WT_hi/lo [256][512]
__global__ void k_splitWT(const float* __restrict__ W, _Float16* __restrict__ hiT,
                          _Float16* __restrict__ loT) {
    int idx = blockIdx.x * 256 + threadIdx.x;
    int n = idx & (H_DIM - 1);
    int k = idx >> 8;
    float x = W[(size_t)k * H_DIM + n];
    _Float16 h = (_Float16)x;
    hiT[(size_t)n * F_DIM + k] = h;
    loT[(size_t)n * F_DIM + k] = (_Float16)(x - (float)h);
}

#define LDP 36   // stride 72B = 18 words, gcd(18,32)=2

#define MFMA3(accv, AH, AL, BH, BL) \
    accv = __builtin_amdgcn_mfma_f32_16x16x32_f16(AH, BH, accv, 0, 0, 0); \
    accv = __builtin_amdgcn_mfma_f32_16x16x32_f16(AH, BL, accv, 0, 0, 0); \
    accv = __builtin_amdgcn_mfma_f32_16x16x32_f16(AL, BH, accv, 0, 0, 0);

#define MFMA_CORE \
    f16x8 ah[4], al[4]; \
    _Pragma("unroll") \
    for (int mi = 0; mi < 4; ++mi) { \
        ah[mi] = *(f16x8*)&Ah[wm * 64 + mi * 16 + lrow][kg * 8]; \
        al[mi] = *(f16x8*)&Al[wm * 64 + mi * 16 + lrow][kg * 8]; \
    } \
    _Pragma("unroll") \
    for (int ni = 0; ni < 4; ++ni) { \
        f16x8 bh = *(f16x8*)&Bh[wn * 64 + ni * 16 + lrow][kg * 8]; \
        f16x8 bl = *(f16x8*)&Bl[wn * 64 + ni * 16 + lrow][kg * 8]; \
        _Pragma("unroll") \
        for (int mi = 0; mi < 4; ++mi) { MFMA3(acc[mi][ni], ah[mi], al[mi], bh, bl) } \
    }

#define WRITE_A_REGS { \
    f16x8 h0, l0, h1, l1; \
    split8v(pa0, pa1, &h0, &l0); \
    split8v(pa2, pa3, &h1, &l1); \
    *(f16x8*)&Ah[sr][skh] = h0; *(f16x8*)&Ah[sr][skh + 8] = h1; \
    *(f16x8*)&Al[sr][skh] = l0; *(f16x8*)&Al[sr][skh + 8] = l1; }

// X = (A @ WT^T + bias) * inv_s; A f32 fused-split (pipelined), WT pre-split f16 (pipelined)
// XCD-swizzled 1-D grid: sibling n-tiles of one m land on the same XCD adjacently.
__global__ __launch_bounds__(256) void k_gemm_mfma(
    const float* __restrict__ A,
    const _Float16* __restrict__ BThi, const _Float16* __restrict__ BTlo,
    const float* __restrict__ bias, const float* __restrict__ inv_s,
    float* __restrict__ X, int K) {
    __shared__ _Float16 Ah[128][LDP], Al[128][LDP], Bh[128][LDP], Bl[128][LDP];
    const int t = threadIdx.x;
    const int lane = t & 63;
    const int wm = (t >> 6) >> 1, wn = (t >> 6) & 1;
    const int lrow = lane & 15, kg = lane >> 4;
    const int bid = blockIdx.x;                       // 0..1023
    const int m0 = (((bid >> 4) << 3) | (bid & 7)) * 128;
    const int n0 = ((bid >> 3) & 1) * 128;
    const int sr = t >> 1, skh = (t & 1) << 4;
    const float* gA = A + (size_t)(m0 + sr) * K + skh;
    const _Float16* gBh = BThi + (size_t)(n0 + sr) * K + skh;
    const _Float16* gBl = BTlo + (size_t)(n0 + sr) * K + skh;
    f32x4_t acc[4][4] = {};
    float4 pa0, pa1, pa2, pa3;
    // prologue: stage tile 0
    pa0 = *(const float4*)(gA + 0);  pa1 = *(const float4*)(gA + 4);
    pa2 = *(const float4*)(gA + 8);  pa3 = *(const float4*)(gA + 12);
    WRITE_A_REGS
    *(float4*)&Bh[sr][skh]     = *(const float4*)(gBh + 0);
    *(float4*)&Bh[sr][skh + 8] = *(const float4*)(gBh + 8);
    *(float4*)&Bl[sr][skh]     = *(const float4*)(gBl + 0);
    *(float4*)&Bl[sr][skh + 8] = *(const float4*)(gBl + 8);
    for (int k0 = 0; k0 < K; k0 += 32) {
        __syncthreads();                       // LDS tile k0 ready
        const bool more = (k0 + 32) < K;
        float4 qb0, qb1, qb2, qb3;
        if (more) {                            // loads for k0+32 hide under MFMA
            pa0 = *(const float4*)(gA + k0 + 32);
            pa1 = *(const float4*)(gA + k0 + 36);
            pa2 = *(const float4*)(gA + k0 + 40);
            pa3 = *(const float4*)(gA + k0 + 44);
            qb0 = *(const float4*)(gBh + k0 + 32);
            qb1 = *(const float4*)(gBh + k0 + 40);
            qb2 = *(const float4*)(gBl + k0 + 32);
            qb3 = *(const float4*)(gBl + k0 + 40);
        }
        MFMA_CORE
        __syncthreads();                       // all waves done reading tile k0
        if (more) {
            WRITE_A_REGS
            *(float4*)&Bh[sr][skh]     = qb0;
            *(float4*)&Bh[sr][skh + 8] = qb1;
            *(float4*)&Bl[sr][skh]     = qb2;
            *(float4*)&Bl[sr][skh + 8] = qb3;
        }
    }
    #pragma unroll
    for (int ni = 0; ni < 4; ++ni) {
        int col = n0 + wn * 64 + ni * 16 + lrow;
        float bc = bias[col];
        #pragma unroll
        for (int mi = 0; mi < 4; ++mi) {
            #pragma unroll
            for (int j = 0; j < 4; ++j) {
                int row = m0 + wm * 64 + mi * 16 + kg * 4 + j;
                X[(size_t)row * H_DIM + col] = (acc[mi][ni][j] + bc) * inv_s[row];
            }
        }
    }
}

// cluster: emb (A, reg-pipelined) and centers (B) f32 fused-split; XCD-swizzled grid
__global__ __launch_bounds__(256) void k_cluster_mfma(
    const float* __restrict__ emb, const float* __restrict__ centers,
    const float* __restrict__ e2, const float* __restrict__ c2,
    unsigned* __restrict__ node_min, unsigned long long* __restrict__ center_min) {
    __shared__ _Float16 Ah[128][LDP], Al[128][LDP], Bh[128][LDP], Bl[128][LDP];
    __shared__ unsigned s_nmin[128];
    __shared__ unsigned long long s_cmin[128];
    const int t = threadIdx.x;
    const int lane = t & 63;
    const int wm = (t >> 6) >> 1, wn = (t >> 6) & 1;
    const int lrow = lane & 15, kg = lane >> 4;
    const int bid = blockIdx.x;                       // 0..2047
    const int m0 = (((bid >> 5) << 3) | (bid & 7)) * 128;
    const int n0 = ((bid >> 3) & 3) * 128;
    const int sr = t >> 1, skh = (t & 1) << 4;
    const int K = H_DIM;
    const float* gA = emb + (size_t)(m0 + sr) * K + skh;
    const float* gB = centers + (size_t)(n0 + sr) * K + skh;
    if (t < 128) { s_nmin[t] = 0x7F800000u; s_cmin[t] = ~0ull; }
    f32x4_t acc[4][4] = {};
    float4 pa0, pa1, pa2, pa3;
    pa0 = *(const float4*)(gA + 0);  pa1 = *(const float4*)(gA + 4);
    pa2 = *(const float4*)(gA + 8);  pa3 = *(const float4*)(gA + 12);
    WRITE_A_REGS
    {
        f16x8 h0, l0, h1, l1;
        float4 b0 = *(const float4*)(gB + 0), b1 = *(const float4*)(gB + 4);
        float4 b2 = *(const float4*)(gB + 8), b3 = *(const float4*)(gB + 12);
        split8v(b0, b1, &h0, &l0);
        split8v(b2, b3, &h1, &l1);
        *(f16x8*)&Bh[sr][skh] = h0; *(f16x8*)&Bh[sr][skh + 8] = h1;
        *(f16x8*)&Bl[sr][skh] = l0; *(f16x8*)&Bl[sr][skh + 8] = l1;
    }
    for (int k0 = 0; k0 < K; k0 += 32) {
        __syncthreads();
        const bool more = (k0 + 32) < K;
        if (more) {
            pa0 = *(const float4*)(gA + k0 + 32);
            pa1 = *(const float4*)(gA + k0 + 36);
            pa2 = *(const float4*)(gA + k0 + 40);
            pa3 = *(const float4*)(gA + k0 + 44);
        }
        MFMA_CORE
        __syncthreads();
        if (more) {
            WRITE_A_REGS
            f16x8 h0, l0, h1, l1;
            float4 b0 = *(const float4*)(gB + k0 + 32), b1 = *(const float4*)(gB + k0 + 36);
            float4 b2 = *(const float4*)(gB + k0 + 40), b3 = *(const float4*)(gB + k0 + 44);
            split8v(b0, b1, &h0, &l0);
            split8v(b2, b3, &h1, &l1);
            *(f16x8*)&Bh[sr][skh] = h0; *(f16x8*)&Bh[sr][skh + 8] = h1;
            *(f16x8*)&Bl[sr][skh] = l0; *(f16x8*)&Bl[sr][skh + 8] = l1;
        }
    }
    float cv[4];
    #pragma unroll
    for (int ni = 0; ni < 4; ++ni) cv[ni] = c2[n0 + wn * 64 + ni * 16 + lrow];
    unsigned long long cb[4] = {~0ull, ~0ull, ~0ull, ~0ull};
    #pragma unroll
    for (int mi = 0; mi < 4; ++mi) {
        #pragma unroll
        for (int j = 0; j < 4; ++j) {
            int lr = wm * 64 + mi * 16 + kg * 4 + j;
            int row = m0 + lr;
            float ev = e2[row];
            float rmin = 3.402823466e+38f;
            #pragma unroll
            for (int ni = 0; ni < 4; ++ni) {
                float d2 = ev + cv[ni] - 2.f * acc[mi][ni][j];
                float d = sqrtf(fmaxf(d2, 1e-12f));
                rmin = fminf(rmin, d);
                unsigned long long pk = ((unsigned long long)__float_as_uint(d) << 32) | (unsigned)row;
                if (pk < cb[ni]) cb[ni] = pk;
            }
            atomicMin(&s_nmin[lr], __float_as_uint(rmin));
        }
    }
    #pragma unroll
    for (int ni = 0; ni < 4; ++ni)
        atomicMin(&s_cmin[wn * 64 + ni * 16 + lrow], cb[ni]);
    __syncthreads();
    if (t < 128) {
        atomicMin(&node_min[m0 + t], s_nmin[t]);
        atomicMin(&center_min[n0 + t], s_cmin[t]);
    }
}

// one wave per node; bucket chunk sorted -> bit-deterministic sum
__global__ __launch_bounds__(256) void k_agg1(
    const float* __restrict__ X, const int* __restrict__ csr_send,
    const int* __restrict__ row_ptr, const float* __restrict__ inv_r,
    float* __restrict__ out_emb) {
    int node = blockIdx.x * 4 + (threadIdx.x >> 6);
    int lane = threadIdx.x & 63;
    int beg = row_ptr[node], end = row_ptr[node + 1];
    float4 acc = {0.f, 0.f, 0.f, 0.f};
    for (int b = beg; b < end; b += 64) {
        int n = min(64, end - b);
        int myS = (lane < n) ? csr_send[b + lane] : 0x7FFFFFFF;
        myS = wave_sort64(myS, lane);
        for (int i = 0; i < n; ++i) {
            int s = __shfl(myS, i);
            float4 x = *(const float4*)&X[(size_t)s * H_DIM + (lane << 2)];
            acc.x += x.x; acc.y += x.y; acc.z += x.z; acc.w += x.w;
        }
    }
    float ir = inv_r[node];
    float4 o;
    o.x = selu_f(acc.x * ir);
    o.y = selu_f(acc.y * ir);
    o.z = selu_f(acc.z * ir);
    o.w = selu_f(acc.w * ir);
    *(float4*)&out_emb[(size_t)node * H_DIM + (lane << 2)] = o;
}

__global__ __launch_bounds__(256) void k_agg2(
    const float* __restrict__ X, const int* __restrict__ csr_send,
    const int* __restrict__ row_ptr, const float* __restrict__ inv_r,
    const float* __restrict__ v, float* __restrict__ out) {
    int node = blockIdx.x * 4 + (threadIdx.x >> 6);
    int lane = threadIdx.x & 63;
    int beg = row_ptr[node], end = row_ptr[node + 1];
    float4 acc = {0.f, 0.f, 0.f, 0.f};
    for (int b = beg; b < end; b += 64) {
        int n = min(64, end - b);
        int myS = (lane < n) ? csr_send[b + lane] : 0x7FFFFFFF;
        myS = wave_sort64(myS, lane);
        for (int i = 0; i < n; ++i) {
            int s = __shfl(myS, i);
            float4 x = *(const float4*)&X[(size_t)s * H_DIM + (lane << 2)];
            acc.x += x.x; acc.y += x.y; acc.z += x.z; acc.w += x.w;
        }
    }
    float ir = inv_r[node];
    float4 vv = *(const float4*)&v[lane << 2];
    float d = selu_f(acc.x * ir) * vv.x + selu_f(acc.y * ir) * vv.y
            + selu_f(acc.z * ir) * vv.z + selu_f(acc.w * ir) * vv.w;
    #pragma unroll
    for (int off = 32; off; off >>= 1) d += __shfl_down(d, off);
    if (lane == 0) out[node] = d;
}

__global__ __launch_bounds__(256) void k_colsum(const float* __restrict__ nodes1,
                                                float* __restrict__ colsum) {
    int t = threadIdx.x;
    size_t r0 = (size_t)blockIdx.x * 64;
    float s = 0.f;
    for (int r = 0; r < 64; ++r) s += nodes1[(r0 + r) * H_DIM + t];
    atomicAdd(&colsum[t], s);
}

__global__ void k_summary_v(const float* __restrict__ colsum, const float* __restrict__ Wb,
                            float* __restrict__ v) {
    __shared__ float s_sum[H_DIM];
    int t = threadIdx.x;
    float m = colsum[t] * (1.f / (float)N_NODES);
    s_sum[t] = 1.f / (1.f + expf(-m));
    __syncthreads();
    float acc = 0.f;
    for (int j = 0; j < H_DIM; ++j) acc += Wb[t * H_DIM + j] * s_sum[j];
    v[t] = acc;
}

__global__ __launch_bounds__(256) void k_normrow(
    float* __restrict__ emb, const float* __restrict__ v,
    float* __restrict__ logits, float* __restrict__ e2) {
    int row = blockIdx.x * 4 + (threadIdx.x >> 6);
    int lane = threadIdx.x & 63;
    float4 a = *(float4*)&emb[(size_t)row * H_DIM + (lane << 2)];
    float4 vv = *(const float4*)&v[lane << 2];
    float d = a.x * vv.x + a.y * vv.y + a.z * vv.z + a.w * vv.w;
    float ss = a.x * a.x + a.y * a.y + a.z * a.z + a.w * a.w;
    #pragma unroll
    for (int off = 32; off; off >>= 1) {
        d += __shfl_xor(d, off);
        ss += __shfl_xor(ss, off);
    }
    if (lane == 0) logits[row] = d;
    float inv = 1.f / sqrtf(ss);
    a.x *= inv; a.y *= inv; a.z *= inv; a.w *= inv;
    *(float4*)&emb[(size_t)row * H_DIM + (lane << 2)] = a;
    float s2 = a.x * a.x + a.y * a.y + a.z * a.z + a.w * a.w;
    #pragma unroll
    for (int off = 32; off; off >>= 1) s2 += __shfl_xor(s2, off);
    if (lane == 0) e2[row] = s2;
}

__global__ __launch_bounds__(256) void k_c2(const float* __restrict__ centers,
                                            float* __restrict__ c2) {
    int row = blockIdx.x * 4 + (threadIdx.x >> 6);
    int lane = threadIdx.x & 63;
    float4 a = *(const float4*)&centers[(size_t)row * H_DIM + (lane << 2)];
    float ss = a.x * a.x + a.y * a.y + a.z * a.z + a.w * a.w;
    #pragma unroll
    for (int off = 32; off; off >>= 1) ss += __shfl_xor(ss, off);
    if (lane == 0) c2[row] = ss;
}

__global__ __launch_bounds__(256) void k_loss(const unsigned* __restrict__ node_min,
                                              double* __restrict__ acc) {
    int i = blockIdx.x * 256 + threadIdx.x;
    float s = __uint_as_float(node_min[i]);
    #pragma unroll
    for (int off = 32; off; off >>= 1) s += __shfl_down(s, off);
    __shared__ float ws[4];
    int lane = threadIdx.x & 63, w = threadIdx.x >> 6;
    if (lane == 0) ws[w] = s;
    __syncthreads();
    if (threadIdx.x == 0) {
        float tot = ws[0] + ws[1] + ws[2] + ws[3];
        atomicAdd(acc, (double)tot);
    }
}

__global__ void k_finalize(const unsigned long long* __restrict__ center_min,
                           const double* __restrict__ loss_acc,
                           float* __restrict__ rep_out, float* __restrict__ loss_out) {
    int t = blockIdx.x * 256 + threadIdx.x;
    if (t < R_REPS) rep_out[t] = (float)(unsigned)(center_min[t] & 0xFFFFFFFFull);
    if (t == 0) *loss_out = (float)(*loss_acc);
}

extern "C" void kernel_launch(void* const* d_in, const int* in_sizes, int n_in,
                              void* d_out, int out_size, void* d_ws, size_t ws_size,
                              hipStream_t stream) {
    const float* nodes   = (const float*)d_in[0];
    const float* c_nodes = (const float*)d_in[1];
    const int* senders   = (const int*)d_in[2];
    const int* receivers = (const int*)d_in[3];
    const float* W       = (const float*)d_in[4];
    const float* bias    = (const float*)d_in[5];
    const float* Wb      = (const float*)d_in[6];
    const float* centers = (const float*)d_in[7];

    float* out = (float*)d_out;
    float* out_emb    = out;
    float* out_cent   = out + (size_t)N_NODES * H_DIM;
    float* out_rep    = out_cent + (size_t)R_REPS * H_DIM;
    float* out_loss   = out_rep + R_REPS;
    float* out_logits = out_loss + 1;

    char* wp = (char*)d_ws;
    unsigned long long* center_min = (unsigned long long*)wp; wp += (size_t)R_REPS * 8;
    double* loss_acc = (double*)wp;             wp += 8;
    float* X = (float*)wp;                      wp += (size_t)N_NODES * H_DIM * 4;
    int* csr_send = (int*)wp;                   wp += (size_t)E_EDGES * 4;
    int* row_ptr = (int*)wp;                    wp += (size_t)(N_NODES + 2) * 4;
    int* cursor = (int*)wp;                     wp += (size_t)N_NODES * 4;
    int* cnt_s = (int*)wp;                      wp += (size_t)N_NODES * 4;
    int* cnt_r = (int*)wp;                      wp += (size_t)N_NODES * 4;
    float* inv_s = (float*)wp;                  wp += (size_t)N_NODES * 4;
    float* inv_r = (float*)wp;                  wp += (size_t)N_NODES * 4;
    float* colsum = (float*)wp;                 wp += (size_t)H_DIM * 4;
    float* v = (float*)wp;                      wp += (size_t)H_DIM * 4;
    float* e2 = (float*)wp;                     wp += (size_t)N_NODES * 4;
    float* c2 = (float*)wp;                     wp += (size_t)R_REPS * 4;
    unsigned* node_min = (unsigned*)wp;         wp += (size_t)N_NODES * 4;
    _Float16* WhiT = (_Float16*)wp;             wp += (size_t)H_DIM * F_DIM * 2;
    _Float16* WloT = (_Float16*)wp;             wp += (size_t)H_DIM * F_DIM * 2;

    k_init<<<N_NODES / 256, 256, 0, stream>>>(cnt_s, cnt_r, colsum, node_min, center_min, loss_acc);
    k_degree<<<E_EDGES / 256, 256, 0, stream>>>(senders, receivers, cnt_s, cnt_r);
    k_invsqrt<<<N_NODES / 256, 256, 0, stream>>>(cnt_s, cnt_r, inv_s, inv_r);
    k_scan<<<1, 1024, 0, stream>>>(cnt_r, row_ptr, cursor);
    k_fill<<<E_EDGES / 256, 256, 0, stream>>>(senders, receivers, cursor, csr_send);
    k_splitWT<<<(F_DIM * H_DIM) / 256, 256, 0, stream>>>(W, WhiT, WloT);

    // GCN1 (1-D XCD-swizzled grid: 1024 blocks)
    k_gemm_mfma<<<1024, 256, 0, stream>>>(nodes, WhiT, WloT, bias, inv_s, X, F_DIM);
    k_agg1<<<N_NODES / 4, 256, 0, stream>>>(X, csr_send, row_ptr, inv_r, out_emb);

    k_colsum<<<N_NODES / 64, 256, 0, stream>>>(out_emb, colsum);
    k_summary_v<<<1, 256, 0, stream>>>(colsum, Wb, v);
    k_normrow<<<N_NODES / 4, 256, 0, stream>>>(out_emb, v, out_logits, e2);
    k_c2<<<R_REPS / 4, 256, 0, stream>>>(centers, c2);

    // cluster (1-D XCD-swizzled grid: 2048 blocks)
    k_cluster_mfma<<<2048, 256, 0, stream>>>(out_emb, centers, e2, c2, node_min, center_min);
    k_loss<<<N_NODES / 256, 256, 0, stream>>>(node_min, loss_acc);
    k_finalize<<<2, 256, 0, stream>>>(center_min, loss_acc, out_rep, out_loss);
    hipMemcpyAsync(out_cent, centers, (size_t)R_REPS * H_DIM * 4, hipMemcpyDeviceToDevice, stream);

    // GCN2 (reuse X; nodes2 never materialized)
    k_gemm_mfma<<<1024, 256, 0, stream>>>(c_nodes, WhiT, WloT, bias, inv_s, X, F_DIM);
    k_agg2<<<N_NODES / 4, 256, 0, stream>>>(X, csr_send, row_ptr, inv_r, v, out_logits + N_NODES);
}